// Round 4
// baseline (192.294 us; speedup 1.0000x reference)
//
#include <hip/hip_runtime.h>

typedef __attribute__((ext_vector_type(8))) short bf16x8;
typedef __attribute__((ext_vector_type(4))) float f32x4;

#define MFMA(a, b, c) __builtin_amdgcn_mfma_f32_16x16x32_bf16(a, b, c, 0, 0, 0)

__device__ __forceinline__ unsigned short f2bf(float f) {
    unsigned u = __builtin_bit_cast(unsigned, f);
    u += 0x7fffu + ((u >> 16) & 1u);
    return (unsigned short)(u >> 16);
}

// async global->LDS DMA, 16B per lane; hardware writes lane i's data at
// (wave-uniform) lds base + i*16B. gptr is per-lane.
__device__ __forceinline__ void gload16(const unsigned short* g, unsigned short* l) {
    __builtin_amdgcn_global_load_lds(
        (const __attribute__((address_space(1))) void*)g,
        (__attribute__((address_space(3))) void*)l, 16, 0, 0);
}

// pack two fp32 -> two bf16 (round-half-up) in one uint via v_perm_b32
__device__ __forceinline__ unsigned pack_bf16(float lo, float hi) {
    unsigned a = __builtin_bit_cast(unsigned, lo) + 0x8000u;
    unsigned b = __builtin_bit_cast(unsigned, hi) + 0x8000u;
    return __builtin_amdgcn_perm(b, a, 0x07060302);  // [hi16(b) : hi16(a)]
}

// ---------------- pass A: convert / transpose / rope tables ----------------

__global__ __launch_bounds__(256) void cvt_bf16(const float* __restrict__ in,
                                                unsigned short* __restrict__ out, int n) {
    int i = (blockIdx.x * 256 + threadIdx.x) * 4;
    if (i < n) {
        float4 f = *(const float4*)(in + i);
        ushort4 u;
        u.x = f2bf(f.x); u.y = f2bf(f.y); u.z = f2bf(f.z); u.w = f2bf(f.w);
        *(ushort4*)(out + i) = u;
    }
}

// in: [R, C] fp32 row-major  ->  out: [C, R] bf16 row-major
__global__ __launch_bounds__(256) void transpose_cvt(const float* __restrict__ in,
                                                     unsigned short* __restrict__ out,
                                                     int R, int C) {
    __shared__ float tile[32][33];
    const int c0 = blockIdx.x * 32, r0 = blockIdx.y * 32;
    const int tr = threadIdx.x >> 3;
    const int j4 = (threadIdx.x & 7) * 4;
    float4 f = *(const float4*)(in + (size_t)(r0 + tr) * C + c0 + j4);
    tile[tr][j4 + 0] = f.x; tile[tr][j4 + 1] = f.y;
    tile[tr][j4 + 2] = f.z; tile[tr][j4 + 3] = f.w;
    __syncthreads();
    ushort4 u;
    u.x = f2bf(tile[j4 + 0][tr]); u.y = f2bf(tile[j4 + 1][tr]);
    u.z = f2bf(tile[j4 + 2][tr]); u.w = f2bf(tile[j4 + 3][tr]);
    *(ushort4*)(out + (size_t)(c0 + tr) * R + r0 + j4) = u;
}

// accurate RoPE tables (libm sincosf: proper range reduction; v_sin_f32 is
// undefined past +-256 revolutions)
__global__ __launch_bounds__(256) void rope_tab(float* __restrict__ cosT,
                                                float* __restrict__ sinT) {
    int i = blockIdx.x * 256 + threadIdx.x;       // 2048*32 = 65536
    int n = i >> 5, f = i & 31;
    float ang = (float)n * exp2f((float)f * -0.4152410118609203f);
    float s, c;
    sincosf(ang, &s, &c);
    cosT[i] = c; sinT[i] = s;
}

// ---------------- GEMM (A [M,K] bf16) x (Bt [N,K] bf16) ----------------
// m97-style: global_load_lds width-16 staging, LDS double buffer, ONE barrier
// per K-iter. Tile 128 rows x 32 cols bf16 = 512 16B-slots; 4 waves x 2 calls
// x 64 lanes = 512, exact coverage. Slot S: row=S>>2, pos=S&3, fetched global
// chunk = pos ^ ((row>>1)&3)  (so each quad's 16 fragment-read lanes spread
// over 8 bank-groups x 2 = 2-way, free). Read: pos = quad ^ ((cc>>1)&3).

template <int EPI>
__global__ __launch_bounds__(256, 3) void gemm_bt(const unsigned short* __restrict__ A,
                                                  const unsigned short* __restrict__ Bt,
                                                  int K, int Ncols,
                                                  unsigned short* __restrict__ oq,
                                                  unsigned short* __restrict__ ok,
                                                  unsigned short* __restrict__ ovt,
                                                  float* __restrict__ of,
                                                  const float* __restrict__ cosT,
                                                  const float* __restrict__ sinT) {
    __shared__ unsigned short As[2][128 * 32];
    __shared__ unsigned short Bs[2][128 * 32];
    const int tid = threadIdx.x;
    const int w = tid >> 6, lane = tid & 63, quad = lane >> 4, cc = lane & 15;
    const int wm = w >> 1, wn = w & 1;
    const int m0 = blockIdx.y * 128, n0 = blockIdx.x * 128;

    size_t aoff[2], boff[2];
#pragma unroll
    for (int t = 0; t < 2; t++) {
        int S = w * 128 + t * 64 + lane;
        int row = S >> 2;
        int c = (S & 3) ^ ((row >> 1) & 3);
        aoff[t] = (size_t)(m0 + row) * K + c * 8;
        boff[t] = (size_t)(n0 + row) * K + c * 8;
    }

    // prime buffer 0
#pragma unroll
    for (int t = 0; t < 2; t++) {
        gload16(A + aoff[t], &As[0][(w * 2 + t) * 512]);
        gload16(Bt + boff[t], &Bs[0][(w * 2 + t) * 512]);
    }
    __syncthreads();

    f32x4 acc[4][4] = {};
    const int rpos = (quad ^ ((cc >> 1) & 3)) * 8;   // swizzled chunk offset (shorts)
    const int nkt = K >> 5;

    for (int kt = 0; kt < nkt; kt++) {
        const int pb = kt & 1;
        if (kt < nkt - 1) {
            const int ko = (kt + 1) * 32;
#pragma unroll
            for (int t = 0; t < 2; t++) {
                gload16(A + aoff[t] + ko, &As[pb ^ 1][(w * 2 + t) * 512]);
                gload16(Bt + boff[t] + ko, &Bs[pb ^ 1][(w * 2 + t) * 512]);
            }
        }
        bf16x8 af[4], bf[4];
#pragma unroll
        for (int i = 0; i < 4; i++)
            af[i] = *(const bf16x8*)&As[pb][(wm * 64 + i * 16 + cc) * 32 + rpos];
#pragma unroll
        for (int i = 0; i < 4; i++)
            bf[i] = *(const bf16x8*)&Bs[pb][(wn * 64 + i * 16 + cc) * 32 + rpos];
#pragma unroll
        for (int i = 0; i < 4; i++)
#pragma unroll
            for (int j = 0; j < 4; j++)
                acc[i][j] = MFMA(af[i], bf[j], acc[i][j]);
        __syncthreads();   // drains this iter's DMA + guards buffer swap
    }

    if (EPI == 0) {
        const int e0 = n0 + wn * 64;
        const int which = e0 >> 10;           // 0=q 1=k 2=v
        const int h = (e0 >> 6) & 15;
        if (which < 2) {
            unsigned short* dst = (which == 0) ? oq : ok;
            const float postscale = (which == 0) ? 0.125f : 1.0f;
#pragma unroll
            for (int mf = 0; mf < 4; mf++) {
#pragma unroll
                for (int r = 0; r < 4; r++) {
                    int mg = m0 + wm * 64 + mf * 16 + quad * 4 + r;
                    int nseq = mg & 2047, b = mg >> 11;
                    float vals[4];
#pragma unroll
                    for (int nf = 0; nf < 4; nf++) vals[nf] = acc[mf][nf][r];
                    size_t rowbase = ((size_t)(b * 16 + h) * 2048 + nseq) * 64;
#pragma unroll
                    for (int nf = 0; nf < 4; nf++) {
                        int d = nf * 16 + cc;
                        int f = d & 31;
                        float cs = cosT[nseq * 32 + f];
                        float sn = sinT[nseq * 32 + f];
                        float partner = vals[nf ^ 2];
                        float outv = (vals[nf] * cs +
                                      ((nf < 2) ? -partner : partner) * sn) * postscale;
                        dst[rowbase + d] = f2bf(outv);
                    }
                }
            }
        } else {
#pragma unroll
            for (int mf = 0; mf < 4; mf++) {
                int mg0 = m0 + wm * 64 + mf * 16 + quad * 4;
                int b = mg0 >> 11, nseq = mg0 & 2047;
#pragma unroll
                for (int nf = 0; nf < 4; nf++) {
                    int d = nf * 16 + cc;
                    ushort4 pk;
                    pk.x = f2bf(acc[mf][nf][0]);
                    pk.y = f2bf(acc[mf][nf][1]);
                    pk.z = f2bf(acc[mf][nf][2]);
                    pk.w = f2bf(acc[mf][nf][3]);
                    *(ushort4*)(ovt + ((size_t)(b * 16 + h) * 64 + d) * 2048 + nseq) = pk;
                }
            }
        }
    } else {
#pragma unroll
        for (int mf = 0; mf < 4; mf++)
#pragma unroll
            for (int nf = 0; nf < 4; nf++)
#pragma unroll
                for (int r = 0; r < 4; r++) {
                    int mg = m0 + wm * 64 + mf * 16 + quad * 4 + r;
                    of[(size_t)mg * Ncols + n0 + wn * 64 + nf * 16 + cc] = acc[mf][nf][r];
                }
    }
}

// ---------------- flash attention v7: kv-gang split, 32 q-rows/wave ----------------
// q,k: [B,H,N,D] bf16 (q pre-scaled by 1/8); vt: [B,H,D,N] bf16; o: [B,N,H*D] bf16
// R3 post-mortem: 3 scheduling fixes flat. Cycle budget per CU-iter (~4275cy):
// MFMA 1240/SIMD (19.4cy/mfma per pipe), softmax VALU ~2000/SIMD, LDS ~2300/CU
// -> barrier phase-lock makes bursts SUM, and totals are set by per-pipe WORK.
// This version halves LDS work and iteration count: 32 q-rows per wave (each K/V
// byte read from LDS feeds 2x the q-rows; bk/bv each feed 2 MFMAs again).
// Occupancy kept at 4 waves/SIMD by kv-GANG split: 8 waves = 4 q-subtiles x
// 2 gangs; gang g handles kv tiles g*16+i with gang-private double-buffered K/V.
// Fixed-bias softmax (p=e^(s-8), no running max) makes kv-partials additive:
// gang 1 stages its partial O + rowsums through LDS once at the end; gang 0
// merges, normalizes, writes. LDS 65KB -> 2 blocks/CU; VGPR capped 128 via
// __launch_bounds__(512,4).

__global__ __launch_bounds__(512, 4) void attn(const unsigned short* __restrict__ q,
                                               const unsigned short* __restrict__ k,
                                               const unsigned short* __restrict__ vt,
                                               unsigned short* __restrict__ o) {
    // [kv][gang][pb][64x64 tile]; fp32 partial-O overlay (stride 68) after loop
    __shared__ unsigned short kvbuf[2][2][2][64 * 64];
    __shared__ float rsr[2][128];
    const int tid = threadIdx.x;
    const int w = tid >> 6, lane = tid & 63, quad = lane >> 4, cc = lane & 15;
    const int g = w & 1, s = w >> 1;
    const int bh = blockIdx.x & 31, qt = blockIdx.x >> 5;

    // Q fragments: wave owns q-rows [s*32, s*32+32)
    const unsigned short* qg = q + ((size_t)bh * 2048 + qt * 128 + s * 32) * 64;
    bf16x8 aq[2][2];
#pragma unroll
    for (int mf = 0; mf < 2; mf++)
#pragma unroll
        for (int kc = 0; kc < 2; kc++)
            aq[mf][kc] = *(const bf16x8*)(qg + (mf * 16 + cc) * 64 + kc * 32 + quad * 8);

    // DMA offsets: gang tile (64x64 = 512 slots of 16B) staged by its 4 waves,
    // 2 gload16 each. Slot S2=(s*2+t)*64+lane; row=S2>>3; chunk c=(S2&7)^(row&7).
    int koff[2], voff[2], ldso[2];
#pragma unroll
    for (int t = 0; t < 2; t++) {
        int S2 = (s * 2 + t) * 64 + lane;
        int row = S2 >> 3;
        int c = (S2 & 7) ^ (row & 7);
        koff[t] = row * 64 + c * 8;       // k rows: stride 64 shorts
        voff[t] = row * 2048 + c * 8;     // vt rows: stride 2048 shorts
        ldso[t] = (s * 2 + t) * 512;
    }

    // gang kv base: tiles g*16 .. g*16+15
    const unsigned short* kgg = k + (size_t)bh * 2048 * 64 + (size_t)g * 16 * 4096;
    const unsigned short* vgg = vt + (size_t)bh * 64 * 2048 + (size_t)g * 16 * 64;

    // prime pb=0 with gang tile 0
#pragma unroll
    for (int t = 0; t < 2; t++) {
        gload16(kgg + koff[t], &kvbuf[0][g][0][ldso[t]]);
        gload16(vgg + voff[t], &kvbuf[1][g][0][ldso[t]]);
    }
    __syncthreads();

    f32x4 oacc[2][4] = {};
    float rs[2] = {};

    for (int i = 0; i < 16; i++) {
        const int pb = i & 1;
        if (i < 15) {
#pragma unroll
            for (int t = 0; t < 2; t++) {
                gload16(kgg + (i + 1) * 4096 + koff[t], &kvbuf[0][g][pb ^ 1][ldso[t]]);
                gload16(vgg + (i + 1) * 64 + voff[t], &kvbuf[1][g][pb ^ 1][ldso[t]]);
            }
        }

        // S^T = MFMA(K-rows, Q-rows): s2[mf][nf] reg r = S[m=mf*16+cc][n=nf*16+quad*4+r]
        const unsigned short* kb = &kvbuf[0][g][pb][0];
        f32x4 s2[2][4] = {};
        __builtin_amdgcn_s_setprio(1);
#pragma unroll
        for (int kc = 0; kc < 2; kc++)
#pragma unroll
            for (int nf = 0; nf < 4; nf++) {
                bf16x8 bk = *(const bf16x8*)&kb[(nf * 16 + cc) * 64 +
                                                ((kc * 4 + quad) ^ (cc & 7)) * 8];
                s2[0][nf] = MFMA(bk, aq[0][kc], s2[0][nf]);
                s2[1][nf] = MFMA(bk, aq[1][kc], s2[1][nf]);
            }
        __builtin_amdgcn_s_setprio(0);

        // p = exp(s-8); in-lane row-sum; pack; permlane-redistribute to PV A-frags
        bf16x8 ap[2][2];
#pragma unroll
        for (int mf = 0; mf < 2; mf++) {
            unsigned X[4][2];
#pragma unroll
            for (int nf = 0; nf < 4; nf++) {
                float p0 = __builtin_amdgcn_exp2f(
                    __builtin_fmaf(s2[mf][nf][0], 1.44269504f, -11.54156036f));
                float p1 = __builtin_amdgcn_exp2f(
                    __builtin_fmaf(s2[mf][nf][1], 1.44269504f, -11.54156036f));
                float p2 = __builtin_amdgcn_exp2f(
                    __builtin_fmaf(s2[mf][nf][2], 1.44269504f, -11.54156036f));
                float p3 = __builtin_amdgcn_exp2f(
                    __builtin_fmaf(s2[mf][nf][3], 1.44269504f, -11.54156036f));
                rs[mf] += (p0 + p1) + (p2 + p3);
                X[nf][0] = pack_bf16(p0, p1);
                X[nf][1] = pack_bf16(p2, p3);
            }
#pragma unroll
            for (int kc = 0; kc < 2; kc++) {
                unsigned a0 = X[kc * 2][0], b0 = X[kc * 2 + 1][0];
                unsigned a1 = X[kc * 2][1], b1 = X[kc * 2 + 1][1];
                asm("v_permlane32_swap_b32 %0, %1" : "+v"(a0), "+v"(b0));
                asm("v_permlane16_swap_b32 %0, %1" : "+v"(a0), "+v"(b0));
                asm("v_permlane32_swap_b32 %0, %1" : "+v"(a1), "+v"(b1));
                asm("v_permlane16_swap_b32 %0, %1" : "+v"(a1), "+v"(b1));
                uint4 dd;
                dd.x = a0; dd.y = a1; dd.z = b0; dd.w = b1;
                ap[mf][kc] = __builtin_bit_cast(bf16x8, dd);
            }
        }

        // O += P V  (bv feeds both mf)
        const unsigned short* vb = &kvbuf[1][g][pb][0];
        __builtin_amdgcn_s_setprio(1);
#pragma unroll
        for (int kc = 0; kc < 2; kc++)
#pragma unroll
            for (int df = 0; df < 4; df++) {
                bf16x8 bv = *(const bf16x8*)&vb[(df * 16 + cc) * 64 +
                                                ((kc * 4 + quad) ^ (cc & 7)) * 8];
                oacc[0][df] = MFMA(ap[0][kc], bv, oacc[0][df]);
                oacc[1][df] = MFMA(ap[1][kc], bv, oacc[1][df]);
            }
        __builtin_amdgcn_s_setprio(0);

        __syncthreads();   // drains this iter's DMA (vmcnt) + guards buffer swap
    }
    // loop-end barrier passed: all tiles consumed, all DMA drained -> kvbuf reusable

    // quad-reduce row-sums (row m = mf*16+cc), publish per-gang
#pragma unroll
    for (int mf = 0; mf < 2; mf++) {
        rs[mf] += __shfl_xor(rs[mf], 16, 64);
        rs[mf] += __shfl_xor(rs[mf], 32, 64);
        if (quad == 0) rsr[g][s * 32 + mf * 16 + cc] = rs[mf];
    }

    // gang 1 stages partial O (fp32, stride 68 to break bank alignment)
    float* po = (float*)&kvbuf[0][0][0][0];    // 128*68*4B = 34.8KB < 64KB buffer
    if (g == 1) {
#pragma unroll
        for (int mf = 0; mf < 2; mf++)
#pragma unroll
            for (int df = 0; df < 4; df++)
#pragma unroll
                for (int r = 0; r < 4; r++)
                    po[(s * 32 + mf * 16 + quad * 4 + r) * 68 + df * 16 + cc] =
                        oacc[mf][df][r];
    }
    __syncthreads();

    // gang 0 merges, normalizes, writes output directly
    if (g == 0) {
        const int b = bh >> 4, h = bh & 15;
#pragma unroll
        for (int mf = 0; mf < 2; mf++) {
            const int rbase = s * 32 + mf * 16 + quad * 4;
            float inv[4];
#pragma unroll
            for (int r = 0; r < 4; r++)
                inv[r] = 1.0f / (rsr[0][rbase + r] + rsr[1][rbase + r]);
#pragma unroll
            for (int r = 0; r < 4; r++) {
                const int grow = qt * 128 + rbase + r;
                unsigned short* og = o + ((size_t)(b * 2048 + grow)) * 1024 + h * 64;
#pragma unroll
                for (int df = 0; df < 4; df++) {
                    float v = (oacc[mf][df][r] + po[(rbase + r) * 68 + df * 16 + cc]) *
                              inv[r];
                    og[df * 16 + cc] = f2bf(v);
                }
            }
        }
    }
}

// ---------------- launcher ----------------

extern "C" void kernel_launch(void* const* d_in, const int* in_sizes, int n_in,
                              void* d_out, int out_size, void* d_ws, size_t ws_size,
                              hipStream_t stream) {
    const float* x = (const float*)d_in[0];
    const float* w_qkv = (const float*)d_in[1];
    const float* w_out = (const float*)d_in[2];
    float* out = (float*)d_out;

    unsigned short* xb    = (unsigned short*)d_ws;        // 4096*1024
    unsigned short* wqkvT = xb + 4096 * 1024;             // 3072*1024
    unsigned short* woutT = wqkvT + 3072 * 1024;          // 1024*1024
    unsigned short* qb    = woutT + 1024 * 1024;          // 2*16*2048*64
    unsigned short* kb    = qb + 2 * 16 * 2048 * 64;
    unsigned short* vtb   = kb + 2 * 16 * 2048 * 64;
    unsigned short* ob    = vtb + 2 * 16 * 2048 * 64;     // 4096*1024
    float* cosT = (float*)(ob + 4096 * 1024);             // 2048*32 fp32
    float* sinT = cosT + 2048 * 32;

    rope_tab<<<256, 256, 0, stream>>>(cosT, sinT);
    cvt_bf16<<<4096, 256, 0, stream>>>(x, xb, 4096 * 1024);
    transpose_cvt<<<dim3(96, 32), 256, 0, stream>>>(w_qkv, wqkvT, 1024, 3072);
    transpose_cvt<<<dim3(32, 32), 256, 0, stream>>>(w_out, woutT, 1024, 1024);
    gemm_bt<0><<<dim3(24, 32), 256, 0, stream>>>(xb, wqkvT, 1024, 3072,
                                                 qb, kb, vtb, nullptr, cosT, sinT);
    attn<<<512, 512, 0, stream>>>(qb, kb, vtb, ob);
    gemm_bt<1><<<dim3(8, 32), 256, 0, stream>>>(ob, woutT, 1024, 1024,
                                                nullptr, nullptr, nullptr, out,
                                                nullptr, nullptr);
}

// Round 5
// 190.973 us; speedup vs baseline: 1.0069x; 1.0069x over previous
//
#include <hip/hip_runtime.h>

typedef __attribute__((ext_vector_type(8))) short bf16x8;
typedef __attribute__((ext_vector_type(4))) float f32x4;

#define MFMA(a, b, c) __builtin_amdgcn_mfma_f32_16x16x32_bf16(a, b, c, 0, 0, 0)

__device__ __forceinline__ unsigned short f2bf(float f) {
    unsigned u = __builtin_bit_cast(unsigned, f);
    u += 0x7fffu + ((u >> 16) & 1u);
    return (unsigned short)(u >> 16);
}

// async global->LDS DMA, 16B per lane; hardware writes lane i's data at
// (wave-uniform) lds base + i*16B. gptr is per-lane.
__device__ __forceinline__ void gload16(const unsigned short* g, unsigned short* l) {
    __builtin_amdgcn_global_load_lds(
        (const __attribute__((address_space(1))) void*)g,
        (__attribute__((address_space(3))) void*)l, 16, 0, 0);
}

// pack two fp32 -> two bf16 (round-half-up) in one uint via v_perm_b32
__device__ __forceinline__ unsigned pack_bf16(float lo, float hi) {
    unsigned a = __builtin_bit_cast(unsigned, lo) + 0x8000u;
    unsigned b = __builtin_bit_cast(unsigned, hi) + 0x8000u;
    return __builtin_amdgcn_perm(b, a, 0x07060302);  // [hi16(b) : hi16(a)]
}

// ---------------- pass A: convert / transpose / rope tables ----------------

__global__ __launch_bounds__(256) void cvt_bf16(const float* __restrict__ in,
                                                unsigned short* __restrict__ out, int n) {
    int i = (blockIdx.x * 256 + threadIdx.x) * 4;
    if (i < n) {
        float4 f = *(const float4*)(in + i);
        ushort4 u;
        u.x = f2bf(f.x); u.y = f2bf(f.y); u.z = f2bf(f.z); u.w = f2bf(f.w);
        *(ushort4*)(out + i) = u;
    }
}

// in: [R, C] fp32 row-major  ->  out: [C, R] bf16 row-major
__global__ __launch_bounds__(256) void transpose_cvt(const float* __restrict__ in,
                                                     unsigned short* __restrict__ out,
                                                     int R, int C) {
    __shared__ float tile[32][33];
    const int c0 = blockIdx.x * 32, r0 = blockIdx.y * 32;
    const int tr = threadIdx.x >> 3;
    const int j4 = (threadIdx.x & 7) * 4;
    float4 f = *(const float4*)(in + (size_t)(r0 + tr) * C + c0 + j4);
    tile[tr][j4 + 0] = f.x; tile[tr][j4 + 1] = f.y;
    tile[tr][j4 + 2] = f.z; tile[tr][j4 + 3] = f.w;
    __syncthreads();
    ushort4 u;
    u.x = f2bf(tile[j4 + 0][tr]); u.y = f2bf(tile[j4 + 1][tr]);
    u.z = f2bf(tile[j4 + 2][tr]); u.w = f2bf(tile[j4 + 3][tr]);
    *(ushort4*)(out + (size_t)(c0 + tr) * R + r0 + j4) = u;
}

// accurate RoPE tables (libm sincosf: proper range reduction; v_sin_f32 is
// undefined past +-256 revolutions)
__global__ __launch_bounds__(256) void rope_tab(float* __restrict__ cosT,
                                                float* __restrict__ sinT) {
    int i = blockIdx.x * 256 + threadIdx.x;       // 2048*32 = 65536
    int n = i >> 5, f = i & 31;
    float ang = (float)n * exp2f((float)f * -0.4152410118609203f);
    float s, c;
    sincosf(ang, &s, &c);
    cosT[i] = c; sinT[i] = s;
}

// ---------------- QKV GEMM: 256x256 tile, BK=64, 8-phase schedule ----------------
// A [4096,1024] bf16 row-major; Bt [3072,1024] bf16 row-major (= W^T rows).
// R4 pivot: attn resisted 4 structural fixes (~55us floor); gemm0 (~25.8 GFLOP,
// est ~50-57us on the m97 128^2 2-barrier structure) is the larger lever. This
// is the guide's 256^2 8-phase template (m198/m201: 1.7x over m97 structure):
// 8 waves (2M x 4N), per-wave C = 128x64 (acc[8][4] f32x4 = 128 VGPR), two
// 64KB LDS buffers (A-ktile 256x64 + B-ktile 256x64 each), K-tile = 64.
// Per K-tile: 4 quadrant-phases of 16 MFMA; af reloaded on mh-change, bf on
// nh-change (order (0,0),(0,1),(1,1),(1,0)): 28 ds_read_b128/ktile/wave, which
// keeps the LDS pipe at ~par with the MFMA pipe. Staging: one full ktile
// (A+B, 8 gload16/thread) issued as a burst at the START of the opposite
// half-iter; its buffer was freed by the gate barrier just before, and it is
// consumed ~4 phases (>=900cy) later, so the vmcnt(0) gate at each half-iter
// boundary drains loads that have long landed (counted-lead pipelining with
// only 2 gates per 128-K iter). Chunk-XOR swizzle identical to the verified
// attn staging (R4: 0 bank conflicts): slot S holds chunk (S&7)^(row&7); read
// chunk k of row r at pos k^(r&7); all reads have row%8 == cc%8.

#define PHASE(AB, BB, MH, NH, DOA, DOB)                                           \
    do {                                                                          \
        if (DOA) {                                                                \
            _Pragma("unroll") for (int mf = 0; mf < 4; mf++)                      \
                _Pragma("unroll") for (int kc = 0; kc < 2; kc++)                  \
                    af[mf][kc] = *(const bf16x8*)&(AB)[                           \
                        (wm * 128 + MH * 64 + mf * 16 + cc) * 64 +                \
                        ((kc * 4 + quad) ^ (cc & 7)) * 8];                        \
        }                                                                         \
        if (DOB) {                                                                \
            _Pragma("unroll") for (int nf = 0; nf < 2; nf++)                      \
                _Pragma("unroll") for (int kc = 0; kc < 2; kc++)                  \
                    bfr[nf][kc] = *(const bf16x8*)&(BB)[                          \
                        (wn * 64 + NH * 32 + nf * 16 + cc) * 64 +                 \
                        ((kc * 4 + quad) ^ (cc & 7)) * 8];                        \
        }                                                                         \
        __builtin_amdgcn_s_setprio(1);                                            \
        _Pragma("unroll") for (int mf = 0; mf < 4; mf++)                          \
            _Pragma("unroll") for (int nf = 0; nf < 2; nf++)                      \
                _Pragma("unroll") for (int kc = 0; kc < 2; kc++)                  \
                    acc[MH * 4 + mf][NH * 2 + nf] = MFMA(                         \
                        af[mf][kc], bfr[nf][kc], acc[MH * 4 + mf][NH * 2 + nf]);  \
        __builtin_amdgcn_s_setprio(0);                                            \
    } while (0)

__global__ __launch_bounds__(512, 2) void gemm_qkv(const unsigned short* __restrict__ A,
                                                   const unsigned short* __restrict__ Bt,
                                                   unsigned short* __restrict__ oq,
                                                   unsigned short* __restrict__ ok,
                                                   unsigned short* __restrict__ ovt,
                                                   const float* __restrict__ cosT,
                                                   const float* __restrict__ sinT) {
    __shared__ unsigned short Ab[2][256 * 64];
    __shared__ unsigned short Bb[2][256 * 64];
    const int tid = threadIdx.x;
    const int w = tid >> 6, lane = tid & 63, quad = lane >> 4, cc = lane & 15;
    const int wm = w >> 2, wn = w & 3;
    const int m0 = blockIdx.y * 256, n0 = blockIdx.x * 256;

    // staging: 2048 16B-slots per matrix-ktile; thread covers S = j*512+w*64+lane
    int soff[4], lb[4];
#pragma unroll
    for (int j = 0; j < 4; j++) {
        int S = j * 512 + w * 64 + lane;
        int row = S >> 3;
        int c = (S & 7) ^ (row & 7);
        soff[j] = row * 1024 + c * 8;         // K=1024 row stride (shorts)
        lb[j] = (j * 512 + w * 64) * 8;       // wave-uniform LDS slot base
    }
    const unsigned short* Ag = A + (size_t)m0 * 1024;
    const unsigned short* Bg = Bt + (size_t)n0 * 1024;

    auto stage = [&](const unsigned short* g, unsigned short* l) {
#pragma unroll
        for (int j = 0; j < 4; j++) gload16(g + soff[j], l + lb[j]);
    };

    f32x4 acc[8][4] = {};
    bf16x8 af[4][2], bfr[2][2];

    // prologue: stage ktile 0 into buf 0
    stage(Ag, &Ab[0][0]);
    stage(Bg, &Bb[0][0]);
    asm volatile("s_waitcnt vmcnt(0)" ::: "memory");
    __builtin_amdgcn_s_barrier();

    for (int t = 0; t < 8; ++t) {
        const int k0 = 2 * t;
        // ---- half X: compute ktile k0 from buf0; stage ktile k0+1 -> buf1 ----
        stage(Ag + (k0 + 1) * 64, &Ab[1][0]);
        stage(Bg + (k0 + 1) * 64, &Bb[1][0]);
        PHASE(Ab[0], Bb[0], 0, 0, true, true);
        __builtin_amdgcn_s_barrier();
        PHASE(Ab[0], Bb[0], 0, 1, false, true);
        __builtin_amdgcn_s_barrier();
        PHASE(Ab[0], Bb[0], 1, 1, true, false);
        __builtin_amdgcn_s_barrier();
        PHASE(Ab[0], Bb[0], 1, 0, false, true);
        asm volatile("s_waitcnt vmcnt(0)" ::: "memory");
        __builtin_amdgcn_s_barrier();    // ktile k0+1 resident; buf0 free
        // ---- half Y: compute ktile k0+1 from buf1; stage ktile k0+2 -> buf0 ----
        if (t < 7) {
            stage(Ag + (k0 + 2) * 64, &Ab[0][0]);
            stage(Bg + (k0 + 2) * 64, &Bb[0][0]);
        }
        PHASE(Ab[1], Bb[1], 0, 0, true, true);
        __builtin_amdgcn_s_barrier();
        PHASE(Ab[1], Bb[1], 0, 1, false, true);
        __builtin_amdgcn_s_barrier();
        PHASE(Ab[1], Bb[1], 1, 1, true, false);
        __builtin_amdgcn_s_barrier();
        PHASE(Ab[1], Bb[1], 1, 0, false, true);
        asm volatile("s_waitcnt vmcnt(0)" ::: "memory");
        __builtin_amdgcn_s_barrier();    // ktile k0+2 resident; buf1 free
    }

    // ---- epilogue: q/k get RoPE + scale; v written transposed ----
    const int e0 = n0 + wn * 64;
    const int which = e0 >> 10;           // 0=q 1=k 2=v
    const int h = (e0 >> 6) & 15;
    if (which < 2) {
        unsigned short* dst = (which == 0) ? oq : ok;
        const float postscale = (which == 0) ? 0.125f : 1.0f;
#pragma unroll
        for (int mf = 0; mf < 8; mf++) {
#pragma unroll
            for (int r = 0; r < 4; r++) {
                int mg = m0 + wm * 128 + mf * 16 + quad * 4 + r;
                int nseq = mg & 2047, b = mg >> 11;
                float vals[4];
#pragma unroll
                for (int nf = 0; nf < 4; nf++) vals[nf] = acc[mf][nf][r];
                size_t rowbase = ((size_t)(b * 16 + h) * 2048 + nseq) * 64;
#pragma unroll
                for (int nf = 0; nf < 4; nf++) {
                    int d = nf * 16 + cc;
                    int f = d & 31;
                    float cs = cosT[nseq * 32 + f];
                    float sn = sinT[nseq * 32 + f];
                    float partner = vals[nf ^ 2];
                    float outv = (vals[nf] * cs +
                                  ((nf < 2) ? -partner : partner) * sn) * postscale;
                    dst[rowbase + d] = f2bf(outv);
                }
            }
        }
    } else {
#pragma unroll
        for (int mf = 0; mf < 8; mf++) {
            int mg0 = m0 + wm * 128 + mf * 16 + quad * 4;
            int b = mg0 >> 11, nseq = mg0 & 2047;
#pragma unroll
            for (int nf = 0; nf < 4; nf++) {
                int d = nf * 16 + cc;
                ushort4 pk;
                pk.x = f2bf(acc[mf][nf][0]);
                pk.y = f2bf(acc[mf][nf][1]);
                pk.z = f2bf(acc[mf][nf][2]);
                pk.w = f2bf(acc[mf][nf][3]);
                *(ushort4*)(ovt + ((size_t)(b * 16 + h) * 64 + d) * 2048 + nseq) = pk;
            }
        }
    }
}

// ---------------- output GEMM (A [M,K] bf16) x (Bt [N,K] bf16) -> fp32 ----------------
// m97-style 128^2 (proven): global_load_lds width-16 staging, LDS double buffer,
// ONE barrier per K-iter.

__global__ __launch_bounds__(256, 3) void gemm_out(const unsigned short* __restrict__ A,
                                                   const unsigned short* __restrict__ Bt,
                                                   int K, int Ncols,
                                                   float* __restrict__ of) {
    __shared__ unsigned short As[2][128 * 32];
    __shared__ unsigned short Bs[2][128 * 32];
    const int tid = threadIdx.x;
    const int w = tid >> 6, lane = tid & 63, quad = lane >> 4, cc = lane & 15;
    const int wm = w >> 1, wn = w & 1;
    const int m0 = blockIdx.y * 128, n0 = blockIdx.x * 128;

    size_t aoff[2], boff[2];
#pragma unroll
    for (int t = 0; t < 2; t++) {
        int S = w * 128 + t * 64 + lane;
        int row = S >> 2;
        int c = (S & 3) ^ ((row >> 1) & 3);
        aoff[t] = (size_t)(m0 + row) * K + c * 8;
        boff[t] = (size_t)(n0 + row) * K + c * 8;
    }

#pragma unroll
    for (int t = 0; t < 2; t++) {
        gload16(A + aoff[t], &As[0][(w * 2 + t) * 512]);
        gload16(Bt + boff[t], &Bs[0][(w * 2 + t) * 512]);
    }
    __syncthreads();

    f32x4 acc[4][4] = {};
    const int rpos = (quad ^ ((cc >> 1) & 3)) * 8;
    const int nkt = K >> 5;

    for (int kt = 0; kt < nkt; kt++) {
        const int pb = kt & 1;
        if (kt < nkt - 1) {
            const int ko = (kt + 1) * 32;
#pragma unroll
            for (int t = 0; t < 2; t++) {
                gload16(A + aoff[t] + ko, &As[pb ^ 1][(w * 2 + t) * 512]);
                gload16(Bt + boff[t] + ko, &Bs[pb ^ 1][(w * 2 + t) * 512]);
            }
        }
        bf16x8 afv[4], bfv[4];
#pragma unroll
        for (int i = 0; i < 4; i++)
            afv[i] = *(const bf16x8*)&As[pb][(wm * 64 + i * 16 + cc) * 32 + rpos];
#pragma unroll
        for (int i = 0; i < 4; i++)
            bfv[i] = *(const bf16x8*)&Bs[pb][(wn * 64 + i * 16 + cc) * 32 + rpos];
#pragma unroll
        for (int i = 0; i < 4; i++)
#pragma unroll
            for (int j = 0; j < 4; j++)
                acc[i][j] = MFMA(afv[i], bfv[j], acc[i][j]);
        __syncthreads();
    }

#pragma unroll
    for (int mf = 0; mf < 4; mf++)
#pragma unroll
        for (int nf = 0; nf < 4; nf++)
#pragma unroll
            for (int r = 0; r < 4; r++) {
                int mg = m0 + wm * 64 + mf * 16 + quad * 4 + r;
                of[(size_t)mg * Ncols + n0 + wn * 64 + nf * 16 + cc] = acc[mf][nf][r];
            }
}

// ---------------- flash attention v4 (best-measured: R1, 54.2us) ----------------
// q,k: [B,H,N,D] bf16 (q pre-scaled by 1/8); vt: [B,H,D,N] bf16; o: [B,N,H*D] bf16
// 512 threads: 8 waves x 16 q-rows; 2 blocks/CU -> 4 waves/SIMD. S^T orientation:
// S^T = MFMA(bk, aq); P staged via wave-private ps rows; per-iter __syncthreads
// drains DMA + guards double buffer.

__global__ __launch_bounds__(512, 4) void attn(const unsigned short* __restrict__ q,
                                               const unsigned short* __restrict__ k,
                                               const unsigned short* __restrict__ vt,
                                               unsigned short* __restrict__ o) {
    __shared__ unsigned short ks[2][64 * 64];
    __shared__ unsigned short vs[2][64 * 64];
    __shared__ unsigned short ps[128 * 72];
    __shared__ float rsb[128];
    const int tid = threadIdx.x;
    const int w = tid >> 6, lane = tid & 63, quad = lane >> 4, cc = lane & 15;
    const int bh = blockIdx.x & 31, qt = blockIdx.x >> 5;

    const unsigned short* qg = q + ((size_t)bh * 2048 + qt * 128 + w * 16) * 64;
    bf16x8 aq[2];
#pragma unroll
    for (int kc = 0; kc < 2; kc++)
        aq[kc] = *(const bf16x8*)(qg + cc * 64 + kc * 32 + quad * 8);

    const int S = w * 64 + lane;
    const int row = S >> 3;
    const int c = (S & 7) ^ (row & 7);
    const int koff = row * 64 + c * 8;
    const int voff = row * 2048 + c * 8;

    const unsigned short* kg0 = k + (size_t)bh * 2048 * 64;
    const unsigned short* vg0 = vt + (size_t)bh * 64 * 2048;

    gload16(kg0 + koff, &ks[0][w * 512]);
    gload16(vg0 + voff, &vs[0][w * 512]);
    __syncthreads();

    f32x4 oacc[4] = {};
    float rs = 0.f;

    for (int kt = 0; kt < 32; kt++) {
        const int pb = kt & 1;
        if (kt < 31) {
            const unsigned short* kb = kg0 + (kt + 1) * 4096;
            const unsigned short* vb = vg0 + (kt + 1) * 64;
            gload16(kb + koff, &ks[pb ^ 1][w * 512]);
            gload16(vb + voff, &vs[pb ^ 1][w * 512]);
        }

        f32x4 s2[4] = {};
        __builtin_amdgcn_s_setprio(1);
#pragma unroll
        for (int kc = 0; kc < 2; kc++) {
#pragma unroll
            for (int nf = 0; nf < 4; nf++) {
                bf16x8 bk = *(const bf16x8*)&ks[pb][(nf * 16 + cc) * 64 +
                                                    ((kc * 4 + quad) ^ (cc & 7)) * 8];
                s2[nf] = MFMA(bk, aq[kc], s2[nf]);
            }
        }
        __builtin_amdgcn_s_setprio(0);

#pragma unroll
        for (int nf = 0; nf < 4; nf++) {
            float p0 = __builtin_amdgcn_exp2f(
                __builtin_fmaf(s2[nf][0], 1.44269504f, -11.54156036f));
            float p1 = __builtin_amdgcn_exp2f(
                __builtin_fmaf(s2[nf][1], 1.44269504f, -11.54156036f));
            float p2 = __builtin_amdgcn_exp2f(
                __builtin_fmaf(s2[nf][2], 1.44269504f, -11.54156036f));
            float p3 = __builtin_amdgcn_exp2f(
                __builtin_fmaf(s2[nf][3], 1.44269504f, -11.54156036f));
            rs += (p0 + p1) + (p2 + p3);
            uint2 pk;
            pk.x = pack_bf16(p0, p1);
            pk.y = pack_bf16(p2, p3);
            *(uint2*)&ps[(w * 16 + cc) * 72 + nf * 16 + quad * 4] = pk;
        }

#pragma unroll
        for (int kc = 0; kc < 2; kc++) {
            bf16x8 ap = *(const bf16x8*)&ps[(w * 16 + cc) * 72 + kc * 32 + quad * 8];
            __builtin_amdgcn_s_setprio(1);
#pragma unroll
            for (int df = 0; df < 4; df++) {
                bf16x8 bv = *(const bf16x8*)&vs[pb][(df * 16 + cc) * 64 +
                                                    ((kc * 4 + quad) ^ (cc & 7)) * 8];
                oacc[df] = MFMA(ap, bv, oacc[df]);
            }
            __builtin_amdgcn_s_setprio(0);
        }

        __syncthreads();
    }

    rs += __shfl_xor(rs, 16, 64);
    rs += __shfl_xor(rs, 32, 64);
    if (quad == 0) rsb[w * 16 + cc] = rs;

    {
        f32x4 rv = *(const f32x4*)&rsb[w * 16 + quad * 4];
        f32x4 inv;
#pragma unroll
        for (int r = 0; r < 4; r++) inv[r] = 1.0f / rv[r];
#pragma unroll
        for (int r = 0; r < 4; r++)
#pragma unroll
            for (int df = 0; df < 4; df++)
                ps[(w * 16 + quad * 4 + r) * 72 + df * 16 + cc] =
                    f2bf(oacc[df][r] * inv[r]);
    }
    __syncthreads();
    {
        const int b = bh >> 4, h = bh & 15;
        int row2 = tid >> 2, seg = tid & 3;
        unsigned short* og =
            o + ((size_t)(b * 2048 + qt * 128 + row2)) * 1024 + h * 64 + seg * 16;
#pragma unroll
        for (int j = 0; j < 2; j++)
            *(uint4*)(og + j * 8) = *(const uint4*)&ps[row2 * 72 + seg * 16 + j * 8];
    }
}

// ---------------- launcher ----------------

extern "C" void kernel_launch(void* const* d_in, const int* in_sizes, int n_in,
                              void* d_out, int out_size, void* d_ws, size_t ws_size,
                              hipStream_t stream) {
    const float* x = (const float*)d_in[0];
    const float* w_qkv = (const float*)d_in[1];
    const float* w_out = (const float*)d_in[2];
    float* out = (float*)d_out;

    unsigned short* xb    = (unsigned short*)d_ws;        // 4096*1024
    unsigned short* wqkvT = xb + 4096 * 1024;             // 3072*1024
    unsigned short* woutT = wqkvT + 3072 * 1024;          // 1024*1024
    unsigned short* qb    = woutT + 1024 * 1024;          // 2*16*2048*64
    unsigned short* kb    = qb + 2 * 16 * 2048 * 64;
    unsigned short* vtb   = kb + 2 * 16 * 2048 * 64;
    unsigned short* ob    = vtb + 2 * 16 * 2048 * 64;     // 4096*1024
    float* cosT = (float*)(ob + 4096 * 1024);             // 2048*32 fp32
    float* sinT = cosT + 2048 * 32;

    rope_tab<<<256, 256, 0, stream>>>(cosT, sinT);
    cvt_bf16<<<4096, 256, 0, stream>>>(x, xb, 4096 * 1024);
    transpose_cvt<<<dim3(96, 32), 256, 0, stream>>>(w_qkv, wqkvT, 1024, 3072);
    transpose_cvt<<<dim3(32, 32), 256, 0, stream>>>(w_out, woutT, 1024, 1024);
    gemm_qkv<<<dim3(12, 16), 512, 0, stream>>>(xb, wqkvT, qb, kb, vtb, cosT, sinT);
    attn<<<512, 512, 0, stream>>>(qb, kb, vtb, ob);
    gemm_out<<<dim3(8, 32), 256, 0, stream>>>(ob, woutT, 1024, 1024, out);
}

// Round 6
// 190.743 us; speedup vs baseline: 1.0081x; 1.0012x over previous
//
#include <hip/hip_runtime.h>

typedef __attribute__((ext_vector_type(8))) short bf16x8;
typedef __attribute__((ext_vector_type(4))) float f32x4;

#define MFMA(a, b, c) __builtin_amdgcn_mfma_f32_16x16x32_bf16(a, b, c, 0, 0, 0)

__device__ __forceinline__ unsigned short f2bf(float f) {
    unsigned u = __builtin_bit_cast(unsigned, f);
    u += 0x7fffu + ((u >> 16) & 1u);
    return (unsigned short)(u >> 16);
}

// async global->LDS DMA, 16B per lane; hardware writes lane i's data at
// (wave-uniform) lds base + i*16B. gptr is per-lane.
__device__ __forceinline__ void gload16(const unsigned short* g, unsigned short* l) {
    __builtin_amdgcn_global_load_lds(
        (const __attribute__((address_space(1))) void*)g,
        (__attribute__((address_space(3))) void*)l, 16, 0, 0);
}

// pack two fp32 -> two bf16 (round-half-up) in one uint via v_perm_b32
__device__ __forceinline__ unsigned pack_bf16(float lo, float hi) {
    unsigned a = __builtin_bit_cast(unsigned, lo) + 0x8000u;
    unsigned b = __builtin_bit_cast(unsigned, hi) + 0x8000u;
    return __builtin_amdgcn_perm(b, a, 0x07060302);  // [hi16(b) : hi16(a)]
}

// ---------------- pass A: convert / transpose / rope tables ----------------

__global__ __launch_bounds__(256) void cvt_bf16(const float* __restrict__ in,
                                                unsigned short* __restrict__ out, int n) {
    int i = (blockIdx.x * 256 + threadIdx.x) * 4;
    if (i < n) {
        float4 f = *(const float4*)(in + i);
        ushort4 u;
        u.x = f2bf(f.x); u.y = f2bf(f.y); u.z = f2bf(f.z); u.w = f2bf(f.w);
        *(ushort4*)(out + i) = u;
    }
}

// in: [R, C] fp32 row-major  ->  out: [C, R] bf16 row-major
__global__ __launch_bounds__(256) void transpose_cvt(const float* __restrict__ in,
                                                     unsigned short* __restrict__ out,
                                                     int R, int C) {
    __shared__ float tile[32][33];
    const int c0 = blockIdx.x * 32, r0 = blockIdx.y * 32;
    const int tr = threadIdx.x >> 3;
    const int j4 = (threadIdx.x & 7) * 4;
    float4 f = *(const float4*)(in + (size_t)(r0 + tr) * C + c0 + j4);
    tile[tr][j4 + 0] = f.x; tile[tr][j4 + 1] = f.y;
    tile[tr][j4 + 2] = f.z; tile[tr][j4 + 3] = f.w;
    __syncthreads();
    ushort4 u;
    u.x = f2bf(tile[j4 + 0][tr]); u.y = f2bf(tile[j4 + 1][tr]);
    u.z = f2bf(tile[j4 + 2][tr]); u.w = f2bf(tile[j4 + 3][tr]);
    *(ushort4*)(out + (size_t)(c0 + tr) * R + r0 + j4) = u;
}

// accurate RoPE tables (libm sincosf: proper range reduction; v_sin_f32 is
// undefined past +-256 revolutions)
__global__ __launch_bounds__(256) void rope_tab(float* __restrict__ cosT,
                                                float* __restrict__ sinT) {
    int i = blockIdx.x * 256 + threadIdx.x;       // 2048*32 = 65536
    int n = i >> 5, f = i & 31;
    float ang = (float)n * exp2f((float)f * -0.4152410118609203f);
    float s, c;
    sincosf(ang, &s, &c);
    cosT[i] = c; sinT[i] = s;
}

// ---------------- QKV GEMM: 256x256, BK=64, faithful 8-phase (R5 fix) ----------------
// R5 post-mortem: previous "8-phase" used vmcnt(0) gates + 16-load bursts ->
// 75% stall at 1 block/CU (MfmaUtil 16%). This version follows the m201
// discipline with a self-staging-quarter scheme that makes per-wave counted
// vmcnt provably race-free:
//   - A-quarter (wm,mh) [64 rows x 64 K] staged by exactly its 4 consumer waves
//     (2 loads/thread); B-quarter (wn,nh) [32 rows] by its 2 consumer waves.
//     => every wave's OWN vmcnt covers every slot it will later ds_read.
//   - per phase: { ds_read quadrant frags; issue ONE quarter-stage (2 gloads)
//     for tile t+1; s_barrier; setprio(1); 16 MFMA; setprio(0); vmcnt(4);
//     s_barrier }.  The wait sits BEFORE the closing barrier, so when any
//     consumer reads after that barrier, all co-stagers' loads have landed.
//   - stage order (A-mh0, B-nh0, B-nh1, A-mh1) vs consumption order
//     (0,0),(0,1),(1,1),(1,0): every vmcnt(4) waits only for loads issued
//     >=2.5 phases (~700cy) earlier; in-flight never drains below 4.
//     Ledger (per wave, tile t, loads for t at pos0-7, t+1 primed '): 
//       gate: out={4..7} need 0-3 -> vm4 | ph0end: out={4..7,0',1'} need 4,5 -> vm4
//       ph1end: out={6,7,0'..3'} need 6,7 -> vm4 | ph2end/ph3end: vm4 lead-only.
//   - last tile peeled: no stages, vmcnt(2)/(0) drains (issued a full tile ago).
// Geometry: 8 waves (2M x 4N), per-wave C 128x64 (acc[8][4]), LDS 128KB
// (2 dbuf x (A 256x64 + B 256x64) bf16), 16 K-tiles. Read swizzle unchanged
// (slot S holds chunk (S&7)^(row&7); verified 0 bank conflicts in R5).

#define PH(ABUF, BBUF, MH, NH, DOA, DOB, VMC, ...)                                \
    do {                                                                          \
        if (DOA) {                                                                \
            _Pragma("unroll") for (int mf = 0; mf < 4; mf++)                      \
                _Pragma("unroll") for (int kc = 0; kc < 2; kc++)                  \
                    af[mf][kc] = *(const bf16x8*)&(ABUF)[                         \
                        (wm * 128 + MH * 64 + mf * 16 + cc) * 64 +                \
                        ((kc * 4 + quad) ^ (cc & 7)) * 8];                        \
        }                                                                         \
        if (DOB) {                                                                \
            _Pragma("unroll") for (int nf = 0; nf < 2; nf++)                      \
                _Pragma("unroll") for (int kc = 0; kc < 2; kc++)                  \
                    bfr[nf][kc] = *(const bf16x8*)&(BBUF)[                        \
                        (wn * 64 + NH * 32 + nf * 16 + cc) * 64 +                 \
                        ((kc * 4 + quad) ^ (cc & 7)) * 8];                        \
        }                                                                         \
        __VA_ARGS__;                                                              \
        asm volatile("s_barrier" ::: "memory");                                   \
        __builtin_amdgcn_s_setprio(1);                                            \
        _Pragma("unroll") for (int mf = 0; mf < 4; mf++)                          \
            _Pragma("unroll") for (int nf = 0; nf < 2; nf++)                      \
                _Pragma("unroll") for (int kc = 0; kc < 2; kc++)                  \
                    acc[MH * 4 + mf][NH * 2 + nf] = MFMA(                         \
                        af[mf][kc], bfr[nf][kc], acc[MH * 4 + mf][NH * 2 + nf]);  \
        __builtin_amdgcn_s_setprio(0);                                            \
        asm volatile("s_waitcnt vmcnt(" VMC ")" ::: "memory");                    \
        asm volatile("s_barrier" ::: "memory");                                   \
    } while (0)

// quarter-stage: 2 gloads by the consumer waves only (offsets precomputed)
#define STAGEA0(t1, buf) { gload16(Ag + gA00 + (t1) * 64, (buf) + lA00);          \
                           gload16(Ag + gA01 + (t1) * 64, (buf) + lA01); }
#define STAGEA1(t1, buf) { gload16(Ag + gA10 + (t1) * 64, (buf) + lA10);          \
                           gload16(Ag + gA11 + (t1) * 64, (buf) + lA11); }
#define STAGEB0(t1, buf) { gload16(Bg + gB00 + (t1) * 64, (buf) + lB00);          \
                           gload16(Bg + gB01 + (t1) * 64, (buf) + lB01); }
#define STAGEB1(t1, buf) { gload16(Bg + gB10 + (t1) * 64, (buf) + lB10);          \
                           gload16(Bg + gB11 + (t1) * 64, (buf) + lB11); }

__global__ __launch_bounds__(512, 2) void gemm_qkv(const unsigned short* __restrict__ A,
                                                   const unsigned short* __restrict__ Bt,
                                                   unsigned short* __restrict__ oq,
                                                   unsigned short* __restrict__ ok,
                                                   unsigned short* __restrict__ ovt,
                                                   const float* __restrict__ cosT,
                                                   const float* __restrict__ sinT) {
    __shared__ unsigned short Ab[2][256 * 64];
    __shared__ unsigned short Bb[2][256 * 64];
    const int tid = threadIdx.x;
    const int w = tid >> 6, lane = tid & 63, quad = lane >> 4, cc = lane & 15;
    const int wm = w >> 2, wn = w & 3;
    const int m0 = blockIdx.y * 256, n0 = blockIdx.x * 256;

    const unsigned short* Ag = A + (size_t)m0 * 1024;
    const unsigned short* Bg = Bt + (size_t)n0 * 1024;

    // staging offsets. A-quarter (wm,mh): slots S=(wm*128+mh*64)*8 + j*256 +
    // wn*64 + lane (4 waves x 2 loads = 512 slots). B-quarter (wn,nh):
    // S=(wn*64+nh*32)*8 + j*128 + wm*64 + lane (2 waves x 2 = 256 slots).
    // slot S: row=S>>3, chunk c=(S&7)^(row&7); global off = row*1024 + c*8;
    // LDS base = (S - lane)*8 shorts (wave-uniform).
    int gA00, gA01, gA10, gA11, lA00, lA01, lA10, lA11;
    int gB00, gB01, gB10, gB11, lB00, lB01, lB10, lB11;
#define MKA(mh, j, G, L)                                                \
    { int S = (wm * 128 + mh * 64) * 8 + j * 256 + wn * 64 + lane;      \
      int r = S >> 3; int c = (S & 7) ^ (r & 7);                        \
      G = r * 1024 + c * 8; L = (S - lane) * 8; }
#define MKB(nh, j, G, L)                                                \
    { int S = (wn * 64 + nh * 32) * 8 + j * 128 + wm * 64 + lane;       \
      int r = S >> 3; int c = (S & 7) ^ (r & 7);                        \
      G = r * 1024 + c * 8; L = (S - lane) * 8; }
    MKA(0, 0, gA00, lA00) MKA(0, 1, gA01, lA01)
    MKA(1, 0, gA10, lA10) MKA(1, 1, gA11, lA11)
    MKB(0, 0, gB00, lB00) MKB(0, 1, gB01, lB01)
    MKB(1, 0, gB10, lB10) MKB(1, 1, gB11, lB11)
#undef MKA
#undef MKB

    f32x4 acc[8][4] = {};
    bf16x8 af[4][2], bfr[2][2];

    // prologue: tile 0 -> buf0, issue order == steady state (pos 0..7)
    STAGEA0(0, &Ab[0][0]);
    STAGEB0(0, &Bb[0][0]);
    STAGEB1(0, &Bb[0][0]);
    STAGEA1(0, &Ab[0][0]);
    asm volatile("s_waitcnt vmcnt(4)" ::: "memory");
    asm volatile("s_barrier" ::: "memory");

    for (int t = 0; t < 15; ++t) {
        const unsigned short* Ac = &Ab[t & 1][0];
        const unsigned short* Bc = &Bb[t & 1][0];
        unsigned short* An = &Ab[(t + 1) & 1][0];
        unsigned short* Bn = &Bb[(t + 1) & 1][0];
        const int t1 = t + 1;
        PH(Ac, Bc, 0, 0, true, true, "4", STAGEA0(t1, An));
        PH(Ac, Bc, 0, 1, false, true, "4", STAGEB0(t1, Bn));
        PH(Ac, Bc, 1, 1, true, false, "4", STAGEB1(t1, Bn));
        PH(Ac, Bc, 1, 0, false, true, "4", STAGEA1(t1, An));
    }
    {   // tile 15 (buf1), no staging; drains are for loads issued a tile ago
        const unsigned short* Ac = &Ab[1][0];
        const unsigned short* Bc = &Bb[1][0];
        PH(Ac, Bc, 0, 0, true, true, "2", );
        PH(Ac, Bc, 0, 1, false, true, "0", );
        PH(Ac, Bc, 1, 1, true, false, "0", );
        PH(Ac, Bc, 1, 0, false, true, "0", );
    }

    // ---- epilogue: q/k get RoPE + scale; v written transposed ----
    const int e0 = n0 + wn * 64;
    const int which = e0 >> 10;           // 0=q 1=k 2=v
    const int h = (e0 >> 6) & 15;
    if (which < 2) {
        unsigned short* dst = (which == 0) ? oq : ok;
        const float postscale = (which == 0) ? 0.125f : 1.0f;
#pragma unroll
        for (int mf = 0; mf < 8; mf++) {
#pragma unroll
            for (int r = 0; r < 4; r++) {
                int mg = m0 + wm * 128 + mf * 16 + quad * 4 + r;
                int nseq = mg & 2047, b = mg >> 11;
                float vals[4];
#pragma unroll
                for (int nf = 0; nf < 4; nf++) vals[nf] = acc[mf][nf][r];
                size_t rowbase = ((size_t)(b * 16 + h) * 2048 + nseq) * 64;
#pragma unroll
                for (int nf = 0; nf < 4; nf++) {
                    int d = nf * 16 + cc;
                    int f = d & 31;
                    float cs = cosT[nseq * 32 + f];
                    float sn = sinT[nseq * 32 + f];
                    float partner = vals[nf ^ 2];
                    float outv = (vals[nf] * cs +
                                  ((nf < 2) ? -partner : partner) * sn) * postscale;
                    dst[rowbase + d] = f2bf(outv);
                }
            }
        }
    } else {
#pragma unroll
        for (int mf = 0; mf < 8; mf++) {
            int mg0 = m0 + wm * 128 + mf * 16 + quad * 4;
            int b = mg0 >> 11, nseq = mg0 & 2047;
#pragma unroll
            for (int nf = 0; nf < 4; nf++) {
                int d = nf * 16 + cc;
                ushort4 pk;
                pk.x = f2bf(acc[mf][nf][0]);
                pk.y = f2bf(acc[mf][nf][1]);
                pk.z = f2bf(acc[mf][nf][2]);
                pk.w = f2bf(acc[mf][nf][3]);
                *(ushort4*)(ovt + ((size_t)(b * 16 + h) * 64 + d) * 2048 + nseq) = pk;
            }
        }
    }
}

// ---------------- output GEMM (A [M,K] bf16) x (Bt [N,K] bf16) -> fp32 ----------------
// m97-style 128^2 (proven): global_load_lds width-16 staging, LDS double buffer,
// ONE barrier per K-iter.

__global__ __launch_bounds__(256, 3) void gemm_out(const unsigned short* __restrict__ A,
                                                   const unsigned short* __restrict__ Bt,
                                                   int K, int Ncols,
                                                   float* __restrict__ of) {
    __shared__ unsigned short As[2][128 * 32];
    __shared__ unsigned short Bs[2][128 * 32];
    const int tid = threadIdx.x;
    const int w = tid >> 6, lane = tid & 63, quad = lane >> 4, cc = lane & 15;
    const int wm = w >> 1, wn = w & 1;
    const int m0 = blockIdx.y * 128, n0 = blockIdx.x * 128;

    size_t aoff[2], boff[2];
#pragma unroll
    for (int t = 0; t < 2; t++) {
        int S = w * 128 + t * 64 + lane;
        int row = S >> 2;
        int c = (S & 3) ^ ((row >> 1) & 3);
        aoff[t] = (size_t)(m0 + row) * K + c * 8;
        boff[t] = (size_t)(n0 + row) * K + c * 8;
    }

#pragma unroll
    for (int t = 0; t < 2; t++) {
        gload16(A + aoff[t], &As[0][(w * 2 + t) * 512]);
        gload16(Bt + boff[t], &Bs[0][(w * 2 + t) * 512]);
    }
    __syncthreads();

    f32x4 acc[4][4] = {};
    const int rpos = (quad ^ ((cc >> 1) & 3)) * 8;
    const int nkt = K >> 5;

    for (int kt = 0; kt < nkt; kt++) {
        const int pb = kt & 1;
        if (kt < nkt - 1) {
            const int ko = (kt + 1) * 32;
#pragma unroll
            for (int t = 0; t < 2; t++) {
                gload16(A + aoff[t] + ko, &As[pb ^ 1][(w * 2 + t) * 512]);
                gload16(Bt + boff[t] + ko, &Bs[pb ^ 1][(w * 2 + t) * 512]);
            }
        }
        bf16x8 afv[4], bfv[4];
#pragma unroll
        for (int i = 0; i < 4; i++)
            afv[i] = *(const bf16x8*)&As[pb][(wm * 64 + i * 16 + cc) * 32 + rpos];
#pragma unroll
        for (int i = 0; i < 4; i++)
            bfv[i] = *(const bf16x8*)&Bs[pb][(wn * 64 + i * 16 + cc) * 32 + rpos];
#pragma unroll
        for (int i = 0; i < 4; i++)
#pragma unroll
            for (int j = 0; j < 4; j++)
                acc[i][j] = MFMA(afv[i], bfv[j], acc[i][j]);
        __syncthreads();
    }

#pragma unroll
    for (int mf = 0; mf < 4; mf++)
#pragma unroll
        for (int nf = 0; nf < 4; nf++)
#pragma unroll
            for (int r = 0; r < 4; r++) {
                int mg = m0 + wm * 64 + mf * 16 + quad * 4 + r;
                of[(size_t)mg * Ncols + n0 + wn * 64 + nf * 16 + cc] = acc[mf][nf][r];
            }
}

// ---------------- flash attention v4 (best-measured: R1, 54.2us) ----------------
// q,k: [B,H,N,D] bf16 (q pre-scaled by 1/8); vt: [B,H,D,N] bf16; o: [B,N,H*D] bf16
// 512 threads: 8 waves x 16 q-rows; 2 blocks/CU -> 4 waves/SIMD. S^T orientation:
// S^T = MFMA(bk, aq); P staged via wave-private ps rows; per-iter __syncthreads
// drains DMA + guards double buffer.

__global__ __launch_bounds__(512, 4) void attn(const unsigned short* __restrict__ q,
                                               const unsigned short* __restrict__ k,
                                               const unsigned short* __restrict__ vt,
                                               unsigned short* __restrict__ o) {
    __shared__ unsigned short ks[2][64 * 64];
    __shared__ unsigned short vs[2][64 * 64];
    __shared__ unsigned short ps[128 * 72];
    __shared__ float rsb[128];
    const int tid = threadIdx.x;
    const int w = tid >> 6, lane = tid & 63, quad = lane >> 4, cc = lane & 15;
    const int bh = blockIdx.x & 31, qt = blockIdx.x >> 5;

    const unsigned short* qg = q + ((size_t)bh * 2048 + qt * 128 + w * 16) * 64;
    bf16x8 aq[2];
#pragma unroll
    for (int kc = 0; kc < 2; kc++)
        aq[kc] = *(const bf16x8*)(qg + cc * 64 + kc * 32 + quad * 8);

    const int S = w * 64 + lane;
    const int row = S >> 3;
    const int c = (S & 7) ^ (row & 7);
    const int koff = row * 64 + c * 8;
    const int voff = row * 2048 + c * 8;

    const unsigned short* kg0 = k + (size_t)bh * 2048 * 64;
    const unsigned short* vg0 = vt + (size_t)bh * 64 * 2048;

    gload16(kg0 + koff, &ks[0][w * 512]);
    gload16(vg0 + voff, &vs[0][w * 512]);
    __syncthreads();

    f32x4 oacc[4] = {};
    float rs = 0.f;

    for (int kt = 0; kt < 32; kt++) {
        const int pb = kt & 1;
        if (kt < 31) {
            const unsigned short* kb = kg0 + (kt + 1) * 4096;
            const unsigned short* vb = vg0 + (kt + 1) * 64;
            gload16(kb + koff, &ks[pb ^ 1][w * 512]);
            gload16(vb + voff, &vs[pb ^ 1][w * 512]);
        }

        f32x4 s2[4] = {};
        __builtin_amdgcn_s_setprio(1);
#pragma unroll
        for (int kc = 0; kc < 2; kc++) {
#pragma unroll
            for (int nf = 0; nf < 4; nf++) {
                bf16x8 bk = *(const bf16x8*)&ks[pb][(nf * 16 + cc) * 64 +
                                                    ((kc * 4 + quad) ^ (cc & 7)) * 8];
                s2[nf] = MFMA(bk, aq[kc], s2[nf]);
            }
        }
        __builtin_amdgcn_s_setprio(0);

#pragma unroll
        for (int nf = 0; nf < 4; nf++) {
            float p0 = __builtin_amdgcn_exp2f(
                __builtin_fmaf(s2[nf][0], 1.44269504f, -11.54156036f));
            float p1 = __builtin_amdgcn_exp2f(
                __builtin_fmaf(s2[nf][1], 1.44269504f, -11.54156036f));
            float p2 = __builtin_amdgcn_exp2f(
                __builtin_fmaf(s2[nf][2], 1.44269504f, -11.54156036f));
            float p3 = __builtin_amdgcn_exp2f(
                __builtin_fmaf(s2[nf][3], 1.44269504f, -11.54156036f));
            rs += (p0 + p1) + (p2 + p3);
            uint2 pk;
            pk.x = pack_bf16(p0, p1);
            pk.y = pack_bf16(p2, p3);
            *(uint2*)&ps[(w * 16 + cc) * 72 + nf * 16 + quad * 4] = pk;
        }

#pragma unroll
        for (int kc = 0; kc < 2; kc++) {
            bf16x8 ap = *(const bf16x8*)&ps[(w * 16 + cc) * 72 + kc * 32 + quad * 8];
            __builtin_amdgcn_s_setprio(1);
#pragma unroll
            for (int df = 0; df < 4; df++) {
                bf16x8 bv = *(const bf16x8*)&vs[pb][(df * 16 + cc) * 64 +
                                                    ((kc * 4 + quad) ^ (cc & 7)) * 8];
                oacc[df] = MFMA(ap, bv, oacc[df]);
            }
            __builtin_amdgcn_s_setprio(0);
        }

        __syncthreads();
    }

    rs += __shfl_xor(rs, 16, 64);
    rs += __shfl_xor(rs, 32, 64);
    if (quad == 0) rsb[w * 16 + cc] = rs;

    {
        f32x4 rv = *(const f32x4*)&rsb[w * 16 + quad * 4];
        f32x4 inv;
#pragma unroll
        for (int r = 0; r < 4; r++) inv[r] = 1.0f / rv[r];
#pragma unroll
        for (int r = 0; r < 4; r++)
#pragma unroll
            for (int df = 0; df < 4; df++)
                ps[(w * 16 + quad * 4 + r) * 72 + df * 16 + cc] =
                    f2bf(oacc[df][r] * inv[r]);
    }
    __syncthreads();
    {
        const int b = bh >> 4, h = bh & 15;
        int row2 = tid >> 2, seg = tid & 3;
        unsigned short* og =
            o + ((size_t)(b * 2048 + qt * 128 + row2)) * 1024 + h * 64 + seg * 16;
#pragma unroll
        for (int j = 0; j < 2; j++)
            *(uint4*)(og + j * 8) = *(const uint4*)&ps[row2 * 72 + seg * 16 + j * 8];
    }
}

// ---------------- launcher ----------------

extern "C" void kernel_launch(void* const* d_in, const int* in_sizes, int n_in,
                              void* d_out, int out_size, void* d_ws, size_t ws_size,
                              hipStream_t stream) {
    const float* x = (const float*)d_in[0];
    const float* w_qkv = (const float*)d_in[1];
    const float* w_out = (const float*)d_in[2];
    float* out = (float*)d_out;

    unsigned short* xb    = (unsigned short*)d_ws;        // 4096*1024
    unsigned short* wqkvT = xb + 4096 * 1024;             // 3072*1024
    unsigned short* woutT = wqkvT + 3072 * 1024;          // 1024*1024
    unsigned short* qb    = woutT + 1024 * 1024;          // 2*16*2048*64
    unsigned short* kb    = qb + 2 * 16 * 2048 * 64;
    unsigned short* vtb   = kb + 2 * 16 * 2048 * 64;
    unsigned short* ob    = vtb + 2 * 16 * 2048 * 64;     // 4096*1024
    float* cosT = (float*)(ob + 4096 * 1024);             // 2048*32 fp32
    float* sinT = cosT + 2048 * 32;

    rope_tab<<<256, 256, 0, stream>>>(cosT, sinT);
    cvt_bf16<<<4096, 256, 0, stream>>>(x, xb, 4096 * 1024);
    transpose_cvt<<<dim3(96, 32), 256, 0, stream>>>(w_qkv, wqkvT, 1024, 3072);
    transpose_cvt<<<dim3(32, 32), 256, 0, stream>>>(w_out, woutT, 1024, 1024);
    gemm_qkv<<<dim3(12, 16), 512, 0, stream>>>(xb, wqkvT, qb, kb, vtb, cosT, sinT);
    attn<<<512, 512, 0, stream>>>(qb, kb, vtb, ob);
    gemm_out<<<dim3(8, 32), 256, 0, stream>>>(ob, woutT, 1024, 1024, out);
}

// Round 7
// 183.714 us; speedup vs baseline: 1.0467x; 1.0383x over previous
//
#include <hip/hip_runtime.h>

typedef __attribute__((ext_vector_type(8))) short bf16x8;
typedef __attribute__((ext_vector_type(4))) float f32x4;

#define MFMA(a, b, c) __builtin_amdgcn_mfma_f32_16x16x32_bf16(a, b, c, 0, 0, 0)

__device__ __forceinline__ unsigned short f2bf(float f) {
    unsigned u = __builtin_bit_cast(unsigned, f);
    u += 0x7fffu + ((u >> 16) & 1u);
    return (unsigned short)(u >> 16);
}

// async global->LDS DMA, 16B per lane; hardware writes lane i's data at
// (wave-uniform) lds base + i*16B. gptr is per-lane.
__device__ __forceinline__ void gload16(const unsigned short* g, unsigned short* l) {
    __builtin_amdgcn_global_load_lds(
        (const __attribute__((address_space(1))) void*)g,
        (__attribute__((address_space(3))) void*)l, 16, 0, 0);
}

// pack two fp32 -> two bf16 (round-half-up) in one uint via v_perm_b32
__device__ __forceinline__ unsigned pack_bf16(float lo, float hi) {
    unsigned a = __builtin_bit_cast(unsigned, lo) + 0x8000u;
    unsigned b = __builtin_bit_cast(unsigned, hi) + 0x8000u;
    return __builtin_amdgcn_perm(b, a, 0x07060302);  // [hi16(b) : hi16(a)]
}

// ---------------- fused pass A: rope tables / convert / 2 transposes ----------------
// R6 post-mortem: cross-round accounting leaves ~35-45us of inter-dispatch gap
// overhead across 7 kernels. All four prep ops are independent -> one kernel,
// grid-partitioned by blockIdx.x. 7 launches -> 4.
//   blocks [0,256):        rope tables (2048*32 entries)
//   blocks [256,4352):     x fp32 -> bf16 (4096*1024 elems, 1024/block)
//   blocks [4352,7424):    w_qkv [1024,3072] -> wqkvT [3072,1024] bf16 (32x32 tiles)
//   blocks [7424,8448):    w_out [1024,1024] -> woutT bf16

__global__ __launch_bounds__(256) void prep(const float* __restrict__ x,
                                            const float* __restrict__ w_qkv,
                                            const float* __restrict__ w_out,
                                            unsigned short* __restrict__ xb,
                                            unsigned short* __restrict__ wqkvT,
                                            unsigned short* __restrict__ woutT,
                                            float* __restrict__ cosT,
                                            float* __restrict__ sinT) {
    __shared__ float tile[32][33];
    const int bx = blockIdx.x, tid = threadIdx.x;

    if (bx < 256) {
        // rope tables (libm sincosf: proper range reduction; v_sin_f32 is
        // undefined past +-256 revolutions)
        int i = bx * 256 + tid;                   // 2048*32 = 65536
        int n = i >> 5, f = i & 31;
        float ang = (float)n * exp2f((float)f * -0.4152410118609203f);
        float s, c;
        sincosf(ang, &s, &c);
        cosT[i] = c; sinT[i] = s;
        return;
    }
    if (bx < 4352) {
        int i = ((bx - 256) * 256 + tid) * 4;     // 4096*1024 total
        float4 f = *(const float4*)(x + i);
        ushort4 u;
        u.x = f2bf(f.x); u.y = f2bf(f.y); u.z = f2bf(f.z); u.w = f2bf(f.w);
        *(ushort4*)(xb + i) = u;
        return;
    }
    // transpose branches: in [R,C] fp32 row-major -> out [C,R] bf16 row-major
    const float* in;
    unsigned short* out;
    int R, C, cx, cy;
    if (bx < 7424) {
        int bid = bx - 4352;                      // grid was (96, 32)
        in = w_qkv; out = wqkvT; R = 1024; C = 3072;
        cx = bid % 96; cy = bid / 96;
    } else {
        int bid = bx - 7424;                      // grid was (32, 32)
        in = w_out; out = woutT; R = 1024; C = 1024;
        cx = bid % 32; cy = bid / 32;
    }
    const int c0 = cx * 32, r0 = cy * 32;
    const int tr = tid >> 3;
    const int j4 = (tid & 7) * 4;
    float4 f = *(const float4*)(in + (size_t)(r0 + tr) * C + c0 + j4);
    tile[tr][j4 + 0] = f.x; tile[tr][j4 + 1] = f.y;
    tile[tr][j4 + 2] = f.z; tile[tr][j4 + 3] = f.w;
    __syncthreads();
    ushort4 u;
    u.x = f2bf(tile[j4 + 0][tr]); u.y = f2bf(tile[j4 + 1][tr]);
    u.z = f2bf(tile[j4 + 2][tr]); u.w = f2bf(tile[j4 + 3][tr]);
    *(ushort4*)(out + (size_t)(c0 + tr) * R + r0 + j4) = u;
}

// ---------------- GEMM (A [M,K] bf16) x (Bt [N,K] bf16) ----------------
// Measured-best structure for this problem (R6 accounting: ~57.7us for EPI=0):
// m97-style 128^2 tile, 768/256 blocks = 3/1 per CU, global_load_lds width-16
// staging, LDS double buffer, ONE barrier per K-iter. Multi-block-per-CU overlap
// is what hides the barrier drain here (m114); both 256^2 8-phase ports measured
// WORSE (60.6us, MfmaUtil 16%) because grid 192 < 256 CUs and 1 block/CU cannot
// overlap its own barrier-locked phases. Tile 128 rows x 32 cols bf16 = 512
// 16B-slots; 4 waves x 2 calls x 64 lanes = 512, exact coverage. Slot S:
// row=S>>2, pos=S&3, fetched chunk = pos ^ ((row>>1)&3); read pos = quad ^
// ((cc>>1)&3) -> 2-way bank aliasing (free).

template <int EPI>
__global__ __launch_bounds__(256, 3) void gemm_bt(const unsigned short* __restrict__ A,
                                                  const unsigned short* __restrict__ Bt,
                                                  int K, int Ncols,
                                                  unsigned short* __restrict__ oq,
                                                  unsigned short* __restrict__ ok,
                                                  unsigned short* __restrict__ ovt,
                                                  float* __restrict__ of,
                                                  const float* __restrict__ cosT,
                                                  const float* __restrict__ sinT) {
    __shared__ unsigned short As[2][128 * 32];
    __shared__ unsigned short Bs[2][128 * 32];
    const int tid = threadIdx.x;
    const int w = tid >> 6, lane = tid & 63, quad = lane >> 4, cc = lane & 15;
    const int wm = w >> 1, wn = w & 1;
    const int m0 = blockIdx.y * 128, n0 = blockIdx.x * 128;

    size_t aoff[2], boff[2];
#pragma unroll
    for (int t = 0; t < 2; t++) {
        int S = w * 128 + t * 64 + lane;
        int row = S >> 2;
        int c = (S & 3) ^ ((row >> 1) & 3);
        aoff[t] = (size_t)(m0 + row) * K + c * 8;
        boff[t] = (size_t)(n0 + row) * K + c * 8;
    }

    // prime buffer 0
#pragma unroll
    for (int t = 0; t < 2; t++) {
        gload16(A + aoff[t], &As[0][(w * 2 + t) * 512]);
        gload16(Bt + boff[t], &Bs[0][(w * 2 + t) * 512]);
    }
    __syncthreads();

    f32x4 acc[4][4] = {};
    const int rpos = (quad ^ ((cc >> 1) & 3)) * 8;   // swizzled chunk offset (shorts)
    const int nkt = K >> 5;

    for (int kt = 0; kt < nkt; kt++) {
        const int pb = kt & 1;
        if (kt < nkt - 1) {
            const int ko = (kt + 1) * 32;
#pragma unroll
            for (int t = 0; t < 2; t++) {
                gload16(A + aoff[t] + ko, &As[pb ^ 1][(w * 2 + t) * 512]);
                gload16(Bt + boff[t] + ko, &Bs[pb ^ 1][(w * 2 + t) * 512]);
            }
        }
        bf16x8 af[4], bf[4];
#pragma unroll
        for (int i = 0; i < 4; i++)
            af[i] = *(const bf16x8*)&As[pb][(wm * 64 + i * 16 + cc) * 32 + rpos];
#pragma unroll
        for (int i = 0; i < 4; i++)
            bf[i] = *(const bf16x8*)&Bs[pb][(wn * 64 + i * 16 + cc) * 32 + rpos];
#pragma unroll
        for (int i = 0; i < 4; i++)
#pragma unroll
            for (int j = 0; j < 4; j++)
                acc[i][j] = MFMA(af[i], bf[j], acc[i][j]);
        __syncthreads();   // drains this iter's DMA + guards buffer swap
    }

    if (EPI == 0) {
        const int e0 = n0 + wn * 64;
        const int which = e0 >> 10;           // 0=q 1=k 2=v
        const int h = (e0 >> 6) & 15;
        if (which < 2) {
            unsigned short* dst = (which == 0) ? oq : ok;
            const float postscale = (which == 0) ? 0.125f : 1.0f;
#pragma unroll
            for (int mf = 0; mf < 4; mf++) {
#pragma unroll
                for (int r = 0; r < 4; r++) {
                    int mg = m0 + wm * 64 + mf * 16 + quad * 4 + r;
                    int nseq = mg & 2047, b = mg >> 11;
                    float vals[4];
#pragma unroll
                    for (int nf = 0; nf < 4; nf++) vals[nf] = acc[mf][nf][r];
                    size_t rowbase = ((size_t)(b * 16 + h) * 2048 + nseq) * 64;
#pragma unroll
                    for (int nf = 0; nf < 4; nf++) {
                        int d = nf * 16 + cc;
                        int f = d & 31;
                        float cs = cosT[nseq * 32 + f];
                        float sn = sinT[nseq * 32 + f];
                        float partner = vals[nf ^ 2];
                        float outv = (vals[nf] * cs +
                                      ((nf < 2) ? -partner : partner) * sn) * postscale;
                        dst[rowbase + d] = f2bf(outv);
                    }
                }
            }
        } else {
#pragma unroll
            for (int mf = 0; mf < 4; mf++) {
                int mg0 = m0 + wm * 64 + mf * 16 + quad * 4;
                int b = mg0 >> 11, nseq = mg0 & 2047;
#pragma unroll
                for (int nf = 0; nf < 4; nf++) {
                    int d = nf * 16 + cc;
                    ushort4 pk;
                    pk.x = f2bf(acc[mf][nf][0]);
                    pk.y = f2bf(acc[mf][nf][1]);
                    pk.z = f2bf(acc[mf][nf][2]);
                    pk.w = f2bf(acc[mf][nf][3]);
                    *(ushort4*)(ovt + ((size_t)(b * 16 + h) * 64 + d) * 2048 + nseq) = pk;
                }
            }
        }
    } else {
#pragma unroll
        for (int mf = 0; mf < 4; mf++)
#pragma unroll
            for (int nf = 0; nf < 4; nf++)
#pragma unroll
                for (int r = 0; r < 4; r++) {
                    int mg = m0 + wm * 64 + mf * 16 + quad * 4 + r;
                    of[(size_t)mg * Ncols + n0 + wn * 64 + nf * 16 + cc] = acc[mf][nf][r];
                }
    }
}

// ---------------- flash attention v4 (best-measured: R1, 54.2us) ----------------
// q,k: [B,H,N,D] bf16 (q pre-scaled by 1/8); vt: [B,H,D,N] bf16; o: [B,N,H*D] bf16
// 512 threads: 8 waves x 16 q-rows; 2 blocks/CU -> 4 waves/SIMD. S^T orientation:
// S^T = MFMA(bk, aq); P staged via wave-private ps rows; per-iter __syncthreads
// drains DMA + guards double buffer.

__global__ __launch_bounds__(512, 4) void attn(const unsigned short* __restrict__ q,
                                               const unsigned short* __restrict__ k,
                                               const unsigned short* __restrict__ vt,
                                               unsigned short* __restrict__ o) {
    __shared__ unsigned short ks[2][64 * 64];
    __shared__ unsigned short vs[2][64 * 64];
    __shared__ unsigned short ps[128 * 72];
    __shared__ float rsb[128];
    const int tid = threadIdx.x;
    const int w = tid >> 6, lane = tid & 63, quad = lane >> 4, cc = lane & 15;
    const int bh = blockIdx.x & 31, qt = blockIdx.x >> 5;

    const unsigned short* qg = q + ((size_t)bh * 2048 + qt * 128 + w * 16) * 64;
    bf16x8 aq[2];
#pragma unroll
    for (int kc = 0; kc < 2; kc++)
        aq[kc] = *(const bf16x8*)(qg + cc * 64 + kc * 32 + quad * 8);

    const int S = w * 64 + lane;
    const int row = S >> 3;
    const int c = (S & 7) ^ (row & 7);
    const int koff = row * 64 + c * 8;
    const int voff = row * 2048 + c * 8;

    const unsigned short* kg0 = k + (size_t)bh * 2048 * 64;
    const unsigned short* vg0 = vt + (size_t)bh * 64 * 2048;

    gload16(kg0 + koff, &ks[0][w * 512]);
    gload16(vg0 + voff, &vs[0][w * 512]);
    __syncthreads();

    f32x4 oacc[4] = {};
    float rs = 0.f;

    for (int kt = 0; kt < 32; kt++) {
        const int pb = kt & 1;
        if (kt < 31) {
            const unsigned short* kb = kg0 + (kt + 1) * 4096;
            const unsigned short* vb = vg0 + (kt + 1) * 64;
            gload16(kb + koff, &ks[pb ^ 1][w * 512]);
            gload16(vb + voff, &vs[pb ^ 1][w * 512]);
        }

        f32x4 s2[4] = {};
        __builtin_amdgcn_s_setprio(1);
#pragma unroll
        for (int kc = 0; kc < 2; kc++) {
#pragma unroll
            for (int nf = 0; nf < 4; nf++) {
                bf16x8 bk = *(const bf16x8*)&ks[pb][(nf * 16 + cc) * 64 +
                                                    ((kc * 4 + quad) ^ (cc & 7)) * 8];
                s2[nf] = MFMA(bk, aq[kc], s2[nf]);
            }
        }
        __builtin_amdgcn_s_setprio(0);

#pragma unroll
        for (int nf = 0; nf < 4; nf++) {
            float p0 = __builtin_amdgcn_exp2f(
                __builtin_fmaf(s2[nf][0], 1.44269504f, -11.54156036f));
            float p1 = __builtin_amdgcn_exp2f(
                __builtin_fmaf(s2[nf][1], 1.44269504f, -11.54156036f));
            float p2 = __builtin_amdgcn_exp2f(
                __builtin_fmaf(s2[nf][2], 1.44269504f, -11.54156036f));
            float p3 = __builtin_amdgcn_exp2f(
                __builtin_fmaf(s2[nf][3], 1.44269504f, -11.54156036f));
            rs += (p0 + p1) + (p2 + p3);
            uint2 pk;
            pk.x = pack_bf16(p0, p1);
            pk.y = pack_bf16(p2, p3);
            *(uint2*)&ps[(w * 16 + cc) * 72 + nf * 16 + quad * 4] = pk;
        }

#pragma unroll
        for (int kc = 0; kc < 2; kc++) {
            bf16x8 ap = *(const bf16x8*)&ps[(w * 16 + cc) * 72 + kc * 32 + quad * 8];
            __builtin_amdgcn_s_setprio(1);
#pragma unroll
            for (int df = 0; df < 4; df++) {
                bf16x8 bv = *(const bf16x8*)&vs[pb][(df * 16 + cc) * 64 +
                                                    ((kc * 4 + quad) ^ (cc & 7)) * 8];
                oacc[df] = MFMA(ap, bv, oacc[df]);
            }
            __builtin_amdgcn_s_setprio(0);
        }

        __syncthreads();
    }

    rs += __shfl_xor(rs, 16, 64);
    rs += __shfl_xor(rs, 32, 64);
    if (quad == 0) rsb[w * 16 + cc] = rs;

    {
        f32x4 rv = *(const f32x4*)&rsb[w * 16 + quad * 4];
        f32x4 inv;
#pragma unroll
        for (int r = 0; r < 4; r++) inv[r] = 1.0f / rv[r];
#pragma unroll
        for (int r = 0; r < 4; r++)
#pragma unroll
            for (int df = 0; df < 4; df++)
                ps[(w * 16 + quad * 4 + r) * 72 + df * 16 + cc] =
                    f2bf(oacc[df][r] * inv[r]);
    }
    __syncthreads();
    {
        const int b = bh >> 4, h = bh & 15;
        int row2 = tid >> 2, seg = tid & 3;
        unsigned short* og =
            o + ((size_t)(b * 2048 + qt * 128 + row2)) * 1024 + h * 64 + seg * 16;
#pragma unroll
        for (int j = 0; j < 2; j++)
            *(uint4*)(og + j * 8) = *(const uint4*)&ps[row2 * 72 + seg * 16 + j * 8];
    }
}

// ---------------- launcher ----------------

extern "C" void kernel_launch(void* const* d_in, const int* in_sizes, int n_in,
                              void* d_out, int out_size, void* d_ws, size_t ws_size,
                              hipStream_t stream) {
    const float* x = (const float*)d_in[0];
    const float* w_qkv = (const float*)d_in[1];
    const float* w_out = (const float*)d_in[2];
    float* out = (float*)d_out;

    unsigned short* xb    = (unsigned short*)d_ws;        // 4096*1024
    unsigned short* wqkvT = xb + 4096 * 1024;             // 3072*1024
    unsigned short* woutT = wqkvT + 3072 * 1024;          // 1024*1024
    unsigned short* qb    = woutT + 1024 * 1024;          // 2*16*2048*64
    unsigned short* kb    = qb + 2 * 16 * 2048 * 64;
    unsigned short* vtb   = kb + 2 * 16 * 2048 * 64;
    unsigned short* ob    = vtb + 2 * 16 * 2048 * 64;     // 4096*1024
    float* cosT = (float*)(ob + 4096 * 1024);             // 2048*32 fp32
    float* sinT = cosT + 2048 * 32;

    prep<<<8448, 256, 0, stream>>>(x, w_qkv, w_out, xb, wqkvT, woutT, cosT, sinT);
    gemm_bt<0><<<dim3(24, 32), 256, 0, stream>>>(xb, wqkvT, 1024, 3072,
                                                 qb, kb, vtb, nullptr, cosT, sinT);
    attn<<<512, 512, 0, stream>>>(qb, kb, vtb, ob);
    gemm_bt<1><<<dim3(8, 32), 256, 0, stream>>>(ob, woutT, 1024, 1024,
                                                nullptr, nullptr, nullptr, out,
                                                nullptr, nullptr);
}